// Round 6
// baseline (562.142 us; speedup 1.0000x reference)
//
#include <hip/hip_runtime.h>
#include <cstdint>
#include <cstddef>

#define B_  2
#define S_  2048
#define D_  2560
#define H_  32
#define HD_ 80

typedef __attribute__((ext_vector_type(8))) short  short8;
typedef __attribute__((ext_vector_type(4))) float  floatx4;

__device__ __forceinline__ float b2f(unsigned short u) {
  union { unsigned int i; float f; } x; x.i = ((unsigned int)u) << 16; return x.f;
}
__device__ __forceinline__ unsigned short f2bf(float f) {
  union { float f; unsigned int i; } x; x.f = f;
  unsigned int u = x.i;
  return (unsigned short)((u + 0x7fffu + ((u >> 16) & 1u)) >> 16);
}

// fused fp32 -> bf16 for all three inputs (one launch)
__global__ void cvt3_kernel(const float* __restrict__ s0, unsigned short* __restrict__ d0, int n0,
                            const float* __restrict__ s1, unsigned short* __restrict__ d1, int n1,
                            const float* __restrict__ s2, unsigned short* __restrict__ d2, int n2) {
  int j = blockIdx.x * 256 + threadIdx.x;
  const float* s; unsigned short* d;
  if (j < n0) { s = s0; d = d0; }
  else {
    j -= n0;
    if (j < n1) { s = s1; d = d1; }
    else { j -= n1; if (j >= n2) return; s = s2; d = d2; }
  }
  const float4 v = ((const float4*)s)[j];
  ushort4 r;
  r.x = f2bf(v.x); r.y = f2bf(v.y); r.z = f2bf(v.z); r.w = f2bf(v.w);
  ((ushort4*)d)[j] = r;
}

#define GLOAD_LDS16(g, l)                                                      \
  __builtin_amdgcn_global_load_lds(                                            \
      (const __attribute__((address_space(1))) void*)(g),                      \
      (__attribute__((address_space(3))) void*)(l), 16, 0, 0)

// ============================================================================
// (MSUB*32) x (NSUB*64) tile, BK=64, 8 waves, double-buffered LDS, 1 barrier
// per K-tile (R4 structure). R6 changes:
//   - REVERTED gemm XCD swizzle. R5 evidence: chunked mapping gave each XCD
//     2 row-tiles x all col-tiles -> streams all of B per XCD; FETCH_SIZE
//     +30% (240->312 GB-equiv), dur +11us. Natural dispatch order clusters
//     L2-resident B col-panels per XCD already.
//   - NSUB template (4 -> 256-col tile; 2 -> 128-col tile). gemm2 uses
//     NSUB=2: 320 blocks fills all 256 CUs round 1 (was 160 = 62.5% fill),
//     keeps full M-reuse, halves B staging + bF reads per block.
// T2 st_16x32 swizzle (bank-conflict measured 0) + T5 setprio retained.
// C[M,N] = A[M,K]*B[N,K]^T + bias[N]; same C mapping as the verified kernel.
// ============================================================================
template <int OUT_BF16, int MSUB, int NSUB>
__global__ __launch_bounds__(512)
void gemm256(const unsigned short* __restrict__ A,
             const unsigned short* __restrict__ Bw,
             const float* __restrict__ bias,
             void* __restrict__ Cv,
             const int M, const int N, const int K) {
  constexpr int ASH  = MSUB * 2048;   // A region per buf, shorts
  constexpr int BSH  = NSUB * 4096;   // B region per buf, shorts
  constexpr int CBUF = ASH + BSH;     // buf stride, shorts
  __shared__ __align__(16) unsigned short sh[2 * CBUF];
  const int tid  = threadIdx.x;
  const int wave = tid >> 6;
  const int lane = tid & 63;
  const int wm = wave >> 2;        // 0..1: wave's m-half of the tile
  const int wn = wave & 3;         // 0..3: wave's n-slice
  const int fr = lane & 15;
  const int fg = lane >> 4;
  const int row0 = (int)blockIdx.y * (MSUB * 32);
  const int col0 = (int)blockIdx.x * (NSUB * 64);
  const unsigned short* Ab = A  + (size_t)row0 * K;
  const unsigned short* Bb = Bw + (size_t)col0 * K;
  // staging: lane's source element inside one 16x32 subtile, pre-swizzled so
  // the linear DMA write realizes LDS[swz(o)] = G[o]  (swz: byte^32 if row>=8)
  const int srow = lane >> 2;                                  // subtile row 0..15
  const int scol = ((lane & 3) << 3) ^ ((lane & 32) ? 16 : 0); // elem col in 0..31
  // ds_read offset inside a subtile (shorts), same involution on the read side
  const int rdoff = fr * 32 + ((fg * 8) ^ ((fr & 8) ? 16 : 0));
  const int aOff = wm * (MSUB == 8 ? 8192 : 2048); // wave's first A row-subtile
  // NSUB==4: B = 2 halves of 128 rows; wave reads half (wn>>1), rowblk (wn&1)*4.
  // NSUB==2: B = 1 half of 128 rows; wave reads rowblks {2*wn, 2*wn+1}.
  const int bOff = ASH + (NSUB == 4 ? (wn >> 1) * 8192 : 0);
  const int rbB  = (NSUB == 4 ? (wn & 1) * 4 : wn * 2);
  const int NT = K >> 6;

  floatx4 acc[MSUB][NSUB] = {};

#define STAGE_HALF(G, matOff, c, h, k0)                                        \
  do {                                                                         \
    _Pragma("unroll")                                                          \
    for (int i_ = 0; i_ < 2; ++i_) {                                           \
      const int s_ = (wave << 1) | i_;                                         \
      const int kk_ = s_ >> 3, rb_ = s_ & 7;                                   \
      GLOAD_LDS16((G) + (size_t)((h) * 128 + rb_ * 16 + srow) * K              \
                      + ((k0) + kk_ * 32 + scol),                              \
                  &sh[(c) * CBUF + (matOff) + (h) * 8192 + s_ * 512]);         \
    }                                                                          \
  } while (0)

  // prologue: tile0 into buf0
  STAGE_HALF(Ab, 0, 0, 0, 0);
  if (MSUB == 8) STAGE_HALF(Ab, 0, 0, 1, 0);
  STAGE_HALF(Bb, ASH, 0, 0, 0);
  if (NSUB == 4) STAGE_HALF(Bb, ASH, 0, 1, 0);
  asm volatile("s_waitcnt vmcnt(0)" ::: "memory");
  __builtin_amdgcn_s_barrier();

  for (int t = 0; t < NT; ++t) {
    const int c  = t & 1;
    const int cb = c * CBUF;
    // ---- stage ALL of tile t+1 into buf[c^1] (free since end of t-1) ----
    if (t + 1 < NT) {
      const int k1 = (t + 1) << 6;
      STAGE_HALF(Ab, 0, c ^ 1, 0, k1);
      if (MSUB == 8) STAGE_HALF(Ab, 0, c ^ 1, 1, k1);
      STAGE_HALF(Bb, ASH, c ^ 1, 0, k1);
      if (NSUB == 4) STAGE_HALF(Bb, ASH, c ^ 1, 1, k1);
    }
    short8 aL[4][2], aH[4][2], bF0[2][2], bF1[2][2];
    // ---- reads: bF0, aL first (MFMA-A operands), bF1 last ----
#pragma unroll
    for (int nj = 0; nj < 2; ++nj)
#pragma unroll
      for (int kk = 0; kk < 2; ++kk)
        bF0[nj][kk] = *(const short8*)&sh[cb + bOff + (kk * 8 + rbB + nj) * 512 + rdoff];
#pragma unroll
    for (int mi = 0; mi < 4; ++mi)
#pragma unroll
      for (int kk = 0; kk < 2; ++kk)
        aL[mi][kk] = *(const short8*)&sh[cb + aOff + (kk * 8 + mi) * 512 + rdoff];
    if (NSUB == 4) {
#pragma unroll
      for (int nj = 0; nj < 2; ++nj)
#pragma unroll
        for (int kk = 0; kk < 2; ++kk)
          bF1[nj][kk] = *(const short8*)&sh[cb + bOff + (kk * 8 + rbB + 2 + nj) * 512 + rdoff];
    }
    // ---- quadrant A: acc[0..3][0..1] = aL x bF0 ----
    __builtin_amdgcn_s_setprio(1);
#pragma unroll
    for (int kk = 0; kk < 2; ++kk)
#pragma unroll
      for (int mi = 0; mi < 4; ++mi)
#pragma unroll
        for (int nj = 0; nj < 2; ++nj)
          acc[mi][nj] = __builtin_amdgcn_mfma_f32_16x16x32_bf16(aL[mi][kk], bF0[nj][kk], acc[mi][nj], 0, 0, 0);
    __builtin_amdgcn_s_setprio(0);
    // ---- reads for aH (MSUB==8) overlap MFMA ----
    if (MSUB == 8) {
#pragma unroll
      for (int mi = 0; mi < 4; ++mi)
#pragma unroll
        for (int kk = 0; kk < 2; ++kk)
          aH[mi][kk] = *(const short8*)&sh[cb + aOff + (kk * 8 + 4 + mi) * 512 + rdoff];
    }
    __builtin_amdgcn_s_setprio(1);
    if (NSUB == 4) {
      // ---- quadrant B: acc[0..3][2..3] = aL x bF1 ----
#pragma unroll
      for (int kk = 0; kk < 2; ++kk)
#pragma unroll
        for (int mi = 0; mi < 4; ++mi)
#pragma unroll
          for (int nj = 0; nj < 2; ++nj)
            acc[mi][2 + nj] = __builtin_amdgcn_mfma_f32_16x16x32_bf16(aL[mi][kk], bF1[nj][kk], acc[mi][2 + nj], 0, 0, 0);
      if (MSUB == 8) {
        // ---- quadrant C: acc[4..7][2..3] = aH x bF1 ----
#pragma unroll
        for (int kk = 0; kk < 2; ++kk)
#pragma unroll
          for (int mi = 0; mi < 4; ++mi)
#pragma unroll
            for (int nj = 0; nj < 2; ++nj)
              acc[4 + mi][2 + nj] = __builtin_amdgcn_mfma_f32_16x16x32_bf16(aH[mi][kk], bF1[nj][kk], acc[4 + mi][2 + nj], 0, 0, 0);
      }
    }
    if (MSUB == 8) {
      // ---- quadrant D: acc[4..7][0..1] = aH x bF0 ----
#pragma unroll
      for (int kk = 0; kk < 2; ++kk)
#pragma unroll
        for (int mi = 0; mi < 4; ++mi)
#pragma unroll
          for (int nj = 0; nj < 2; ++nj)
            acc[4 + mi][nj] = __builtin_amdgcn_mfma_f32_16x16x32_bf16(aH[mi][kk], bF0[nj][kk], acc[4 + mi][nj], 0, 0, 0);
    }
    __builtin_amdgcn_s_setprio(0);
    // ---- single sync point: own DMA (issued a full tile ago) + publish ----
    if (t + 1 < NT) {
      asm volatile("s_waitcnt vmcnt(0)" ::: "memory");
      __builtin_amdgcn_s_barrier();
    }
  }
#undef STAGE_HALF

  // epilogue: identical C mapping to the verified 128^2 kernel
  unsigned short* Cb = (unsigned short*)Cv;
  float* Cf = (float*)Cv;
#pragma unroll
  for (int nj = 0; nj < NSUB; ++nj) {
    const int col = col0 + wn * (NSUB == 4 ? 64 : 32) + nj * 16 + fr;
    const float bv = bias[col];
#pragma unroll
    for (int mi = 0; mi < MSUB; ++mi) {
      const int rowb = row0 + wm * (MSUB * 16) + mi * 16 + fg * 4;
#pragma unroll
      for (int r = 0; r < 4; ++r) {
        const float v = acc[mi][nj][r] + bv;
        const size_t idx = (size_t)(rowb + r) * N + col;
        if (OUT_BF16) Cb[idx] = f2bf(v);
        else          Cf[idx] = v;
      }
    }
  }
}

// qkv[B,S,3,H,HD] bf16 -> Q,K [B,H,S,HD] bf16; rope; Q scaled by (1/sqrt(80))*log2(e).
__global__ void rope_kernel(const unsigned short* __restrict__ qkv,
                            unsigned short* __restrict__ Q,
                            unsigned short* __restrict__ K) {
  const int idx = blockIdx.x * 256 + threadIdx.x;
  if (idx >= B_ * S_ * H_) return;
  const int h = idx & (H_ - 1);
  const int s = (idx >> 5) & (S_ - 1);
  const int b = idx >> 16;
  const unsigned short* row = qkv + (size_t)(b * S_ + s) * (3 * D_);
  const size_t obase = ((size_t)(b * H_ + h) * S_ + s) * HD_;

  float cc[16], ssn[16];
#pragma unroll
  for (int i = 0; i < 16; i++) {
    const float ang = (float)s * exp2f((float)i * -0.83048202372184059f);
    ssn[i] = sinf(ang);
    cc[i]  = cosf(ang);
  }
  {
    const float QS = 0.11180339887498949f * 1.4426950408889634f;
    const uint4* src = (const uint4*)(row + h * HD_);
    float f[80], g[80];
#pragma unroll
    for (int i = 0; i < 10; i++) {
      uint4 t = src[i];
      const unsigned short* w = (const unsigned short*)&t;
#pragma unroll
      for (int j = 0; j < 8; j++) f[i * 8 + j] = b2f(w[j]);
    }
#pragma unroll
    for (int i = 0; i < 16; i++) {
      g[i]      = f[i] * cc[i] - f[i + 16] * ssn[i];
      g[i + 16] = f[i] * ssn[i] + f[i + 16] * cc[i];
    }
#pragma unroll
    for (int i = 32; i < 80; i++) g[i] = f[i];
    uint4* dst = (uint4*)(Q + obase);
#pragma unroll
    for (int i = 0; i < 10; i++) {
      uint4 t;
      unsigned short* w = (unsigned short*)&t;
#pragma unroll
      for (int j = 0; j < 8; j++) w[j] = f2bf(g[i * 8 + j] * QS);
      dst[i] = t;
    }
  }
  {
    const uint4* src = (const uint4*)(row + (H_ + h) * HD_);
    float f[32], g[32];
#pragma unroll
    for (int i = 0; i < 4; i++) {
      uint4 t = src[i];
      const unsigned short* w = (const unsigned short*)&t;
#pragma unroll
      for (int j = 0; j < 8; j++) f[i * 8 + j] = b2f(w[j]);
    }
#pragma unroll
    for (int i = 0; i < 16; i++) {
      g[i]      = f[i] * cc[i] - f[i + 16] * ssn[i];
      g[i + 16] = f[i] * ssn[i] + f[i + 16] * cc[i];
    }
    uint4* dst = (uint4*)(K + obase);
#pragma unroll
    for (int i = 0; i < 4; i++) {
      uint4 t;
      unsigned short* w = (unsigned short*)&t;
#pragma unroll
      for (int j = 0; j < 8; j++) w[j] = f2bf(g[i * 8 + j]);
      dst[i] = t;
    }
#pragma unroll
    for (int i = 4; i < 10; i++) dst[i] = src[i];
  }
}

// V slice of qkv -> tiles Vtile[bh][s-chunk64][80][64], cols XOR-swizzled by (d&7)*8.
__global__ __launch_bounds__(256)
void vtrans_kernel(const unsigned short* __restrict__ qkv, unsigned short* __restrict__ Vt) {
  __shared__ unsigned short T[64][88];
  const int tid = threadIdx.x;
  const int bh = blockIdx.y;
  const int b = bh >> 5, h = bh & 31;
  const int tile = blockIdx.x;
  const int s0 = tile * 64;
  for (int t = tid; t < 640; t += 256) {
    const int r = t / 10, c = t % 10;
    const size_t src = ((size_t)((b * S_ + s0 + r) * 3) + 2) * D_ + h * HD_ + c * 8;
    *(uint4*)&T[r][c * 8] = *(const uint4*)&qkv[src];
  }
  __syncthreads();
  unsigned short* tb = Vt + ((size_t)bh * 32 + tile) * 5120;
  for (int t = tid; t < 640; t += 256) {
    const int d = t / 8, sc = t % 8;
    uint4 o;
    unsigned short* w = (unsigned short*)&o;
#pragma unroll
    for (int j = 0; j < 8; j++) w[j] = T[sc * 8 + j][d];
    *(uint4*)&tb[d * 64 + ((sc * 8) ^ ((d & 7) * 8))] = o;
  }
}

// ============================================================================
// MFMA flash attention, S^T form. R5 structure (kept): double-buffered K/V
// staging, ONE barrier per chunk; top-of-chunk vmcnt(0) waits on DMA issued a
// full chunk earlier (latency hidden under compute). XCD swizzle clusters
// 8 bh per XCD for K/V L2 reuse; heavy-first qt order preserved per XCD.
// ============================================================================
__global__ __launch_bounds__(256, 3)
void attn_mfma(const unsigned short* __restrict__ Qg,
               const unsigned short* __restrict__ Kg,
               const unsigned short* __restrict__ Vtg,
               unsigned short* __restrict__ ctx) {
  __shared__ unsigned short Ks[2][64 * 80];  // [buf][k][80] (DMA-contiguous)
  __shared__ unsigned short Vs[2][80 * 64];  // [buf][d][64], XOR-swizzled cols
  __shared__ unsigned short Ts[4][32 * 40];  // per-wave P^T staging, pad 40

  const int tid  = threadIdx.x;
  const int wave = tid >> 6;
  const int lane = tid & 63;
  const int fr   = lane & 15;
  const int fg   = lane >> 4;
  // XCD swizzle: 1024 blocks -> 8 XCDs x 128; bh = p>>4 clusters per XCD.
  int p = (int)(blockIdx.y * gridDim.x + blockIdx.x);
  p = (p & 7) * 128 + (p >> 3);
  const int bh = p >> 4;
  const int qt = 15 - (p & 15);              // heavy tiles first (per XCD)
  const int qbase = (qt << 7) + wave * 32;

  const unsigned short* Qrow  = Qg  + (size_t)bh * S_ * HD_;
  const unsigned short* Krow  = Kg  + (size_t)bh * S_ * HD_;
  const unsigned short* Vtile = Vtg + (size_t)bh * 32 * 5120;

  // Q fragments (B-operand): rows q, contiguous d; 3rd step zeroed for fg>=2
  short8 qf[2][3];
  const short8 zfrag = {};
#pragma unroll
  for (int mi = 0; mi < 2; mi++) {
    const unsigned short* qp = Qrow + (size_t)(qbase + mi * 16 + fr) * HD_;
    qf[mi][0] = *(const short8*)&qp[fg * 8];
    qf[mi][1] = *(const short8*)&qp[32 + fg * 8];
    qf[mi][2] = (fg < 2) ? *(const short8*)&qp[64 + fg * 8] : zfrag;
  }

  floatx4 accOT[5][2] = {};   // O^T: lane holds O[q=mi*16+fr][d=dt*16+fg*4+r]
  float l_part[2] = {0.f, 0.f};

  const int nch = 2 * qt + 2;

  // 20 DMA instrs per chunk, 5 per wave: j 0..9 -> K, j 10..19 -> V.
#define STAGE_CHUNK(c)                                                         \
  do {                                                                         \
    const int buf_ = (c) & 1;                                                  \
    const unsigned short* Kt_ = Krow + (size_t)(c) * 64 * HD_;                 \
    const unsigned short* Vt_ = Vtile + (size_t)(c) * 5120;                    \
    _Pragma("unroll")                                                          \
    for (int u_ = 0; u_ < 5; ++u_) {                                           \
      const int j_ = wave * 5 + u_;                                            \
      if (j_ < 10) GLOAD_LDS16(Kt_ + j_ * 512 + lane * 8, &Ks[buf_][j_ * 512]);\
      else GLOAD_LDS16(Vt_ + (j_ - 10) * 512 + lane * 8,                       \
                       &Vs[buf_][(j_ - 10) * 512]);                            \
    }                                                                          \
  } while (0)

  STAGE_CHUNK(0);

  for (int c = 0; c < nch; c++) {
    const int k0 = c * 64;
    const int buf = c & 1;
    asm volatile("s_waitcnt vmcnt(0)" ::: "memory");  // chunk c landed (issued 1 chunk ago)
    __builtin_amdgcn_s_barrier();                     // all waves: c landed, c-1 reads done
    if (c + 1 < nch) STAGE_CHUNK(c + 1);

    // S^T = K Q^T: accST[ni][mi] lane holds P[q=mi*16+fr][k=ni*16+fg*4+r]
    floatx4 accST[4][2] = {};
#pragma unroll
    for (int ni = 0; ni < 4; ni++) {
      const unsigned short* kp = &Ks[buf][(ni * 16 + fr) * 80];
      const short8 kf0 = *(const short8*)&kp[fg * 8];
      const short8 kf1 = *(const short8*)&kp[32 + fg * 8];
      const short8 kf2 = *(const short8*)&kp[64 + (fg & 1) * 8];  // fg>=2: qf side is zero
      accST[ni][0] = __builtin_amdgcn_mfma_f32_16x16x32_bf16(kf0, qf[0][0], accST[ni][0], 0, 0, 0);
      accST[ni][1] = __builtin_amdgcn_mfma_f32_16x16x32_bf16(kf0, qf[1][0], accST[ni][1], 0, 0, 0);
      accST[ni][0] = __builtin_amdgcn_mfma_f32_16x16x32_bf16(kf1, qf[0][1], accST[ni][0], 0, 0, 0);
      accST[ni][1] = __builtin_amdgcn_mfma_f32_16x16x32_bf16(kf1, qf[1][1], accST[ni][1], 0, 0, 0);
      accST[ni][0] = __builtin_amdgcn_mfma_f32_16x16x32_bf16(kf2, qf[0][2], accST[ni][0], 0, 0, 0);
      accST[ni][1] = __builtin_amdgcn_mfma_f32_16x16x32_bf16(kf2, qf[1][2], accST[ni][1], 0, 0, 0);
    }

    // causal mask (diagonal-crossing chunks only)
    if (k0 + 63 > qbase) {
#pragma unroll
      for (int ni = 0; ni < 4; ni++)
#pragma unroll
        for (int mi = 0; mi < 2; mi++) {
          const int qg = qbase + mi * 16 + fr;
#pragma unroll
          for (int r = 0; r < 4; r++) {
            const int kg = k0 + ni * 16 + fg * 4 + r;
            if (kg > qg) accST[ni][mi][r] = -1e30f;
          }
        }
    }

    // per 32-key half: exp2 -> packed P^T to LDS -> PV MFMA
#pragma unroll
    for (int hh = 0; hh < 2; hh++) {
#pragma unroll
      for (int nh = 0; nh < 2; nh++) {
        const int ni = hh * 2 + nh;
#pragma unroll
        for (int mi = 0; mi < 2; mi++) {
          const float p0 = __builtin_amdgcn_exp2f(accST[ni][mi][0]);
          const float p1 = __builtin_amdgcn_exp2f(accST[ni][mi][1]);
          const float p2 = __builtin_amdgcn_exp2f(accST[ni][mi][2]);
          const float p3 = __builtin_amdgcn_exp2f(accST[ni][mi][3]);
          l_part[mi] += (p0 + p1) + (p2 + p3);
          uint2 w;
          w.x = (unsigned)f2bf(p0) | ((unsigned)f2bf(p1) << 16);
          w.y = (unsigned)f2bf(p2) | ((unsigned)f2bf(p3) << 16);
          *(uint2*)&Ts[wave][(mi * 16 + fr) * 40 + nh * 16 + fg * 4] = w;
        }
      }
      // wave-local write->read; compiler inserts lgkmcnt
      const short8 pf0 = *(const short8*)&Ts[wave][fr * 40 + fg * 8];
      const short8 pf1 = *(const short8*)&Ts[wave][(16 + fr) * 40 + fg * 8];
      const int vcol = hh * 32 + fg * 8;
#pragma unroll
      for (int dt = 0; dt < 5; dt++) {
        const short8 vf = *(const short8*)&Vs[buf][(dt * 16 + fr) * 64 + (vcol ^ ((fr & 7) * 8))];
        accOT[dt][0] = __builtin_amdgcn_mfma_f32_16x16x32_bf16(vf, pf0, accOT[dt][0], 0, 0, 0);
        accOT[dt][1] = __builtin_amdgcn_mfma_f32_16x16x32_bf16(vf, pf1, accOT[dt][1], 0, 0, 0);
      }
    }
  }
#undef STAGE_CHUNK

  // epilogue: l reduce across fg lanes; packed b64 ctx stores (4 consecutive d)
  const int b = bh >> 5, h2 = bh & 31;
#pragma unroll
  for (int mi = 0; mi < 2; mi++) {
    float s = l_part[mi];
    s += __shfl_xor(s, 16);
    s += __shfl_xor(s, 32);
    const float inv = 1.f / s;
    const size_t rowoff = (size_t)(b * S_ + qbase + mi * 16 + fr) * D_ + h2 * HD_;
#pragma unroll
    for (int dt = 0; dt < 5; dt++) {
      const float v0 = accOT[dt][mi][0] * inv;
      const float v1 = accOT[dt][mi][1] * inv;
      const float v2 = accOT[dt][mi][2] * inv;
      const float v3 = accOT[dt][mi][3] * inv;
      uint2 w;
      w.x = (unsigned)f2bf(v0) | ((unsigned)f2bf(v1) << 16);
      w.y = (unsigned)f2bf(v2) | ((unsigned)f2bf(v3) << 16);
      *(uint2*)&ctx[rowoff + dt * 16 + fg * 4] = w;
    }
  }
}

extern "C" void kernel_launch(void* const* d_in, const int* in_sizes, int n_in,
                              void* d_out, int out_size, void* d_ws, size_t ws_size,
                              hipStream_t stream) {
  (void)in_sizes; (void)n_in; (void)out_size; (void)ws_size;
  const float* x      = (const float*)d_in[0];
  const float* wqkv_w = (const float*)d_in[1];
  const float* wqkv_b = (const float*)d_in[2];
  const float* out_w  = (const float*)d_in[3];
  const float* out_b  = (const float*)d_in[4];
  char* ws = (char*)d_ws;

  unsigned short* Xb    = (unsigned short*)(ws + 0);          // 4096x2560 bf16
  unsigned short* Wqkvb = (unsigned short*)(ws + 20971520);   // 7680x2560 bf16 (dead after gemm1)
  unsigned short* qkv   = (unsigned short*)(ws + 60293120);   // 4096x7680 bf16
  unsigned short* Qb    = (unsigned short*)(ws + 123207680);  // [B,H,S,80] bf16
  unsigned short* Kb    = (unsigned short*)(ws + 144179200);  // [B,H,S,80] bf16
  unsigned short* Woutb = (unsigned short*)(ws + 165150720);  // 2560x2560 bf16; end 178.3 MB
  unsigned short* ctx   = Xb;                                 // Xb dead after gemm1
  unsigned short* Vtile = (unsigned short*)(ws + 34078720);   // 21.0 MB in dead Wqkvb tail

  cvt3_kernel<<<35840, 256, 0, stream>>>(x, Xb, 2621440,
                                         wqkv_w, Wqkvb, 4915200,
                                         out_w, Woutb, 1638400);
  gemm256<1, 8, 4><<<dim3(30, 16), 512, 0, stream>>>(Xb, Wqkvb, wqkv_b, (void*)qkv, 4096, 7680, 2560);
  rope_kernel<<<512, 256, 0, stream>>>(qkv, Qb, Kb);
  vtrans_kernel<<<dim3(32, 64), 256, 0, stream>>>(qkv, Vtile);
  attn_mfma<<<dim3(16, 64), 256, 0, stream>>>(Qb, Kb, Vtile, ctx);
  gemm256<0, 8, 2><<<dim3(20, 16), 512, 0, stream>>>(ctx, Woutb, out_b, d_out, 4096, 2560, 2560);
}

// Round 7
// 558.313 us; speedup vs baseline: 1.0069x; 1.0069x over previous
//
#include <hip/hip_runtime.h>
#include <cstdint>
#include <cstddef>

#define B_  2
#define S_  2048
#define D_  2560
#define H_  32
#define HD_ 80

typedef __attribute__((ext_vector_type(8))) short  short8;
typedef __attribute__((ext_vector_type(4))) float  floatx4;

__device__ __forceinline__ float b2f(unsigned short u) {
  union { unsigned int i; float f; } x; x.i = ((unsigned int)u) << 16; return x.f;
}
__device__ __forceinline__ unsigned short f2bf(float f) {
  union { float f; unsigned int i; } x; x.f = f;
  unsigned int u = x.i;
  return (unsigned short)((u + 0x7fffu + ((u >> 16) & 1u)) >> 16);
}

// fused fp32 -> bf16 for all three inputs (one launch)
__global__ void cvt3_kernel(const float* __restrict__ s0, unsigned short* __restrict__ d0, int n0,
                            const float* __restrict__ s1, unsigned short* __restrict__ d1, int n1,
                            const float* __restrict__ s2, unsigned short* __restrict__ d2, int n2) {
  int j = blockIdx.x * 256 + threadIdx.x;
  const float* s; unsigned short* d;
  if (j < n0) { s = s0; d = d0; }
  else {
    j -= n0;
    if (j < n1) { s = s1; d = d1; }
    else { j -= n1; if (j >= n2) return; s = s2; d = d2; }
  }
  const float4 v = ((const float4*)s)[j];
  ushort4 r;
  r.x = f2bf(v.x); r.y = f2bf(v.y); r.z = f2bf(v.z); r.w = f2bf(v.w);
  ((ushort4*)d)[j] = r;
}

#define GLOAD_LDS16(g, l)                                                      \
  __builtin_amdgcn_global_load_lds(                                            \
      (const __attribute__((address_space(1))) void*)(g),                      \
      (__attribute__((address_space(3))) void*)(l), 16, 0, 0)

// ============================================================================
// (MSUB*32) x (NSUB*64) tile, BK=64, 8 waves, double-buffered LDS, 1 barrier
// per K-tile (R4 structure, natural dispatch order — gemm XCD swizzle hurt,
// R5 evidence). R7: gemm2 reverted to NSUB=4 dim3(10,16) — R6's NSUB=2 at
// 320 blocks regressed +29us (A staged by 20 instead of 10 col-blocks, MFMA
// halves but A-reads don't, x1.25 rounds). 62.5% fill for 1 round beats that.
// T2 st_16x32 swizzle (bank-conflict measured 0) + T5 setprio retained.
// C[M,N] = A[M,K]*B[N,K]^T + bias[N]; same C mapping as the verified kernel.
// ============================================================================
template <int OUT_BF16, int MSUB, int NSUB>
__global__ __launch_bounds__(512)
void gemm256(const unsigned short* __restrict__ A,
             const unsigned short* __restrict__ Bw,
             const float* __restrict__ bias,
             void* __restrict__ Cv,
             const int M, const int N, const int K) {
  constexpr int ASH  = MSUB * 2048;   // A region per buf, shorts
  constexpr int BSH  = NSUB * 4096;   // B region per buf, shorts
  constexpr int CBUF = ASH + BSH;     // buf stride, shorts
  __shared__ __align__(16) unsigned short sh[2 * CBUF];
  const int tid  = threadIdx.x;
  const int wave = tid >> 6;
  const int lane = tid & 63;
  const int wm = wave >> 2;        // 0..1: wave's m-half of the tile
  const int wn = wave & 3;         // 0..3: wave's n-slice
  const int fr = lane & 15;
  const int fg = lane >> 4;
  const int row0 = (int)blockIdx.y * (MSUB * 32);
  const int col0 = (int)blockIdx.x * (NSUB * 64);
  const unsigned short* Ab = A  + (size_t)row0 * K;
  const unsigned short* Bb = Bw + (size_t)col0 * K;
  // staging: lane's source element inside one 16x32 subtile, pre-swizzled so
  // the linear DMA write realizes LDS[swz(o)] = G[o]  (swz: byte^32 if row>=8)
  const int srow = lane >> 2;                                  // subtile row 0..15
  const int scol = ((lane & 3) << 3) ^ ((lane & 32) ? 16 : 0); // elem col in 0..31
  // ds_read offset inside a subtile (shorts), same involution on the read side
  const int rdoff = fr * 32 + ((fg * 8) ^ ((fr & 8) ? 16 : 0));
  const int aOff = wm * (MSUB == 8 ? 8192 : 2048); // wave's first A row-subtile
  const int bOff = ASH + (NSUB == 4 ? (wn >> 1) * 8192 : 0);
  const int rbB  = (NSUB == 4 ? (wn & 1) * 4 : wn * 2);
  const int NT = K >> 6;

  floatx4 acc[MSUB][NSUB] = {};

#define STAGE_HALF(G, matOff, c, h, k0)                                        \
  do {                                                                         \
    _Pragma("unroll")                                                          \
    for (int i_ = 0; i_ < 2; ++i_) {                                           \
      const int s_ = (wave << 1) | i_;                                         \
      const int kk_ = s_ >> 3, rb_ = s_ & 7;                                   \
      GLOAD_LDS16((G) + (size_t)((h) * 128 + rb_ * 16 + srow) * K              \
                      + ((k0) + kk_ * 32 + scol),                              \
                  &sh[(c) * CBUF + (matOff) + (h) * 8192 + s_ * 512]);         \
    }                                                                          \
  } while (0)

  // prologue: tile0 into buf0
  STAGE_HALF(Ab, 0, 0, 0, 0);
  if (MSUB == 8) STAGE_HALF(Ab, 0, 0, 1, 0);
  STAGE_HALF(Bb, ASH, 0, 0, 0);
  if (NSUB == 4) STAGE_HALF(Bb, ASH, 0, 1, 0);
  asm volatile("s_waitcnt vmcnt(0)" ::: "memory");
  __builtin_amdgcn_s_barrier();

  for (int t = 0; t < NT; ++t) {
    const int c  = t & 1;
    const int cb = c * CBUF;
    // ---- stage ALL of tile t+1 into buf[c^1] (free since end of t-1) ----
    if (t + 1 < NT) {
      const int k1 = (t + 1) << 6;
      STAGE_HALF(Ab, 0, c ^ 1, 0, k1);
      if (MSUB == 8) STAGE_HALF(Ab, 0, c ^ 1, 1, k1);
      STAGE_HALF(Bb, ASH, c ^ 1, 0, k1);
      if (NSUB == 4) STAGE_HALF(Bb, ASH, c ^ 1, 1, k1);
    }
    short8 aL[4][2], aH[4][2], bF0[2][2], bF1[2][2];
    // ---- reads: bF0, aL first (MFMA-A operands), bF1 last ----
#pragma unroll
    for (int nj = 0; nj < 2; ++nj)
#pragma unroll
      for (int kk = 0; kk < 2; ++kk)
        bF0[nj][kk] = *(const short8*)&sh[cb + bOff + (kk * 8 + rbB + nj) * 512 + rdoff];
#pragma unroll
    for (int mi = 0; mi < 4; ++mi)
#pragma unroll
      for (int kk = 0; kk < 2; ++kk)
        aL[mi][kk] = *(const short8*)&sh[cb + aOff + (kk * 8 + mi) * 512 + rdoff];
    if (NSUB == 4) {
#pragma unroll
      for (int nj = 0; nj < 2; ++nj)
#pragma unroll
        for (int kk = 0; kk < 2; ++kk)
          bF1[nj][kk] = *(const short8*)&sh[cb + bOff + (kk * 8 + rbB + 2 + nj) * 512 + rdoff];
    }
    // ---- quadrant A: acc[0..3][0..1] = aL x bF0 ----
    __builtin_amdgcn_s_setprio(1);
#pragma unroll
    for (int kk = 0; kk < 2; ++kk)
#pragma unroll
      for (int mi = 0; mi < 4; ++mi)
#pragma unroll
        for (int nj = 0; nj < 2; ++nj)
          acc[mi][nj] = __builtin_amdgcn_mfma_f32_16x16x32_bf16(aL[mi][kk], bF0[nj][kk], acc[mi][nj], 0, 0, 0);
    __builtin_amdgcn_s_setprio(0);
    // ---- reads for aH (MSUB==8) overlap MFMA ----
    if (MSUB == 8) {
#pragma unroll
      for (int mi = 0; mi < 4; ++mi)
#pragma unroll
        for (int kk = 0; kk < 2; ++kk)
          aH[mi][kk] = *(const short8*)&sh[cb + aOff + (kk * 8 + 4 + mi) * 512 + rdoff];
    }
    __builtin_amdgcn_s_setprio(1);
    if (NSUB == 4) {
      // ---- quadrant B: acc[0..3][2..3] = aL x bF1 ----
#pragma unroll
      for (int kk = 0; kk < 2; ++kk)
#pragma unroll
        for (int mi = 0; mi < 4; ++mi)
#pragma unroll
          for (int nj = 0; nj < 2; ++nj)
            acc[mi][2 + nj] = __builtin_amdgcn_mfma_f32_16x16x32_bf16(aL[mi][kk], bF1[nj][kk], acc[mi][2 + nj], 0, 0, 0);
      if (MSUB == 8) {
        // ---- quadrant C: acc[4..7][2..3] = aH x bF1 ----
#pragma unroll
        for (int kk = 0; kk < 2; ++kk)
#pragma unroll
          for (int mi = 0; mi < 4; ++mi)
#pragma unroll
            for (int nj = 0; nj < 2; ++nj)
              acc[4 + mi][2 + nj] = __builtin_amdgcn_mfma_f32_16x16x32_bf16(aH[mi][kk], bF1[nj][kk], acc[4 + mi][2 + nj], 0, 0, 0);
      }
    }
    if (MSUB == 8) {
      // ---- quadrant D: acc[4..7][0..1] = aH x bF0 ----
#pragma unroll
      for (int kk = 0; kk < 2; ++kk)
#pragma unroll
        for (int mi = 0; mi < 4; ++mi)
#pragma unroll
          for (int nj = 0; nj < 2; ++nj)
            acc[4 + mi][nj] = __builtin_amdgcn_mfma_f32_16x16x32_bf16(aH[mi][kk], bF0[nj][kk], acc[4 + mi][nj], 0, 0, 0);
    }
    __builtin_amdgcn_s_setprio(0);
    // ---- single sync point: own DMA (issued a full tile ago) + publish ----
    if (t + 1 < NT) {
      asm volatile("s_waitcnt vmcnt(0)" ::: "memory");
      __builtin_amdgcn_s_barrier();
    }
  }
#undef STAGE_HALF

  // epilogue: identical C mapping to the verified 128^2 kernel
  unsigned short* Cb = (unsigned short*)Cv;
  float* Cf = (float*)Cv;
#pragma unroll
  for (int nj = 0; nj < NSUB; ++nj) {
    const int col = col0 + wn * (NSUB == 4 ? 64 : 32) + nj * 16 + fr;
    const float bv = bias[col];
#pragma unroll
    for (int mi = 0; mi < MSUB; ++mi) {
      const int rowb = row0 + wm * (MSUB * 16) + mi * 16 + fg * 4;
#pragma unroll
      for (int r = 0; r < 4; ++r) {
        const float v = acc[mi][nj][r] + bv;
        const size_t idx = (size_t)(rowb + r) * N + col;
        if (OUT_BF16) Cb[idx] = f2bf(v);
        else          Cf[idx] = v;
      }
    }
  }
}

// qkv[B,S,3,H,HD] bf16 -> Q,K [B,H,S,HD] bf16; rope; Q scaled by (1/sqrt(80))*log2(e).
__global__ void rope_kernel(const unsigned short* __restrict__ qkv,
                            unsigned short* __restrict__ Q,
                            unsigned short* __restrict__ K) {
  const int idx = blockIdx.x * 256 + threadIdx.x;
  if (idx >= B_ * S_ * H_) return;
  const int h = idx & (H_ - 1);
  const int s = (idx >> 5) & (S_ - 1);
  const int b = idx >> 16;
  const unsigned short* row = qkv + (size_t)(b * S_ + s) * (3 * D_);
  const size_t obase = ((size_t)(b * H_ + h) * S_ + s) * HD_;

  float cc[16], ssn[16];
#pragma unroll
  for (int i = 0; i < 16; i++) {
    const float ang = (float)s * exp2f((float)i * -0.83048202372184059f);
    ssn[i] = sinf(ang);
    cc[i]  = cosf(ang);
  }
  {
    const float QS = 0.11180339887498949f * 1.4426950408889634f;
    const uint4* src = (const uint4*)(row + h * HD_);
    float f[80], g[80];
#pragma unroll
    for (int i = 0; i < 10; i++) {
      uint4 t = src[i];
      const unsigned short* w = (const unsigned short*)&t;
#pragma unroll
      for (int j = 0; j < 8; j++) f[i * 8 + j] = b2f(w[j]);
    }
#pragma unroll
    for (int i = 0; i < 16; i++) {
      g[i]      = f[i] * cc[i] - f[i + 16] * ssn[i];
      g[i + 16] = f[i] * ssn[i] + f[i + 16] * cc[i];
    }
#pragma unroll
    for (int i = 32; i < 80; i++) g[i] = f[i];
    uint4* dst = (uint4*)(Q + obase);
#pragma unroll
    for (int i = 0; i < 10; i++) {
      uint4 t;
      unsigned short* w = (unsigned short*)&t;
#pragma unroll
      for (int j = 0; j < 8; j++) w[j] = f2bf(g[i * 8 + j] * QS);
      dst[i] = t;
    }
  }
  {
    const uint4* src = (const uint4*)(row + (H_ + h) * HD_);
    float f[32], g[32];
#pragma unroll
    for (int i = 0; i < 4; i++) {
      uint4 t = src[i];
      const unsigned short* w = (const unsigned short*)&t;
#pragma unroll
      for (int j = 0; j < 8; j++) f[i * 8 + j] = b2f(w[j]);
    }
#pragma unroll
    for (int i = 0; i < 16; i++) {
      g[i]      = f[i] * cc[i] - f[i + 16] * ssn[i];
      g[i + 16] = f[i] * ssn[i] + f[i + 16] * cc[i];
    }
    uint4* dst = (uint4*)(K + obase);
#pragma unroll
    for (int i = 0; i < 4; i++) {
      uint4 t;
      unsigned short* w = (unsigned short*)&t;
#pragma unroll
      for (int j = 0; j < 8; j++) w[j] = f2bf(g[i * 8 + j]);
      dst[i] = t;
    }
#pragma unroll
    for (int i = 4; i < 10; i++) dst[i] = src[i];
  }
}

// V slice of qkv -> tiles Vtile[bh][s-chunk64][80][64], cols XOR-swizzled by (d&7)*8.
__global__ __launch_bounds__(256)
void vtrans_kernel(const unsigned short* __restrict__ qkv, unsigned short* __restrict__ Vt) {
  __shared__ unsigned short T[64][88];
  const int tid = threadIdx.x;
  const int bh = blockIdx.y;
  const int b = bh >> 5, h = bh & 31;
  const int tile = blockIdx.x;
  const int s0 = tile * 64;
  for (int t = tid; t < 640; t += 256) {
    const int r = t / 10, c = t % 10;
    const size_t src = ((size_t)((b * S_ + s0 + r) * 3) + 2) * D_ + h * HD_ + c * 8;
    *(uint4*)&T[r][c * 8] = *(const uint4*)&qkv[src];
  }
  __syncthreads();
  unsigned short* tb = Vt + ((size_t)bh * 32 + tile) * 5120;
  for (int t = tid; t < 640; t += 256) {
    const int d = t / 8, sc = t % 8;
    uint4 o;
    unsigned short* w = (unsigned short*)&o;
#pragma unroll
    for (int j = 0; j < 8; j++) w[j] = T[sc * 8 + j][d];
    *(uint4*)&tb[d * 64 + ((sc * 8) ^ ((d & 7) * 8))] = o;
  }
}

// ============================================================================
// MFMA flash attention, S^T form. R7: 256 queries/block via 8 waves (512 thr),
// per-wave structure identical to the verified 4-wave kernel (32 q/wave, same
// fragment math, same accumulation order -> identical numerics). Why:
//   - chunk-block-units per bh drop 272 -> 144 (-47% K/V DMA + barriers);
//   - LDS 61.4 KB -> 2 blocks/CU; __launch_bounds__(512,4) caps VGPR at 128
//     -> 16 waves/CU (was 12). To fit 128, the chunk body is split into two
//     32-key halves (QK half -> softmax half -> PV half): peak accST = 16
//     regs instead of 32. Same value order per half -> bitwise-same results.
// Double-buffered staging + one barrier per chunk kept from R5 (top-of-chunk
// vmcnt(0) waits on DMA issued a full chunk earlier). 512 blocks, all
// co-resident; XCD swizzle clusters 8 bh/XCD; heavy-first qt per XCD.
// ============================================================================
__global__ __launch_bounds__(512, 4)
void attn_mfma(const unsigned short* __restrict__ Qg,
               const unsigned short* __restrict__ Kg,
               const unsigned short* __restrict__ Vtg,
               unsigned short* __restrict__ ctx) {
  __shared__ unsigned short Ks[2][64 * 80];  // [buf][k][80] (DMA-contiguous)
  __shared__ unsigned short Vs[2][80 * 64];  // [buf][d][64], XOR-swizzled cols
  __shared__ unsigned short Ts[8][32 * 40];  // per-wave P^T staging, pad 40

  const int tid  = threadIdx.x;
  const int wave = tid >> 6;                 // 0..7
  const int lane = tid & 63;
  const int fr   = lane & 15;
  const int fg   = lane >> 4;
  // XCD swizzle: 512 blocks -> 8 XCDs x 64; bh = p>>3 clusters 8 bh per XCD.
  int p = (int)(blockIdx.y * gridDim.x + blockIdx.x);
  p = (p & 7) * 64 + (p >> 3);
  const int bh = p >> 3;
  const int qt = 7 - (p & 7);                // heavy tiles first (per XCD)
  const int qbase = (qt << 8) + wave * 32;   // 256 q per block

  const unsigned short* Qrow  = Qg  + (size_t)bh * S_ * HD_;
  const unsigned short* Krow  = Kg  + (size_t)bh * S_ * HD_;
  const unsigned short* Vtile = Vtg + (size_t)bh * 32 * 5120;

  // Q fragments (B-operand): rows q, contiguous d; 3rd step zeroed for fg>=2
  short8 qf[2][3];
  const short8 zfrag = {};
#pragma unroll
  for (int mi = 0; mi < 2; mi++) {
    const unsigned short* qp = Qrow + (size_t)(qbase + mi * 16 + fr) * HD_;
    qf[mi][0] = *(const short8*)&qp[fg * 8];
    qf[mi][1] = *(const short8*)&qp[32 + fg * 8];
    qf[mi][2] = (fg < 2) ? *(const short8*)&qp[64 + fg * 8] : zfrag;
  }

  floatx4 accOT[5][2] = {};   // O^T: lane holds O[q=mi*16+fr][d=dt*16+fg*4+r]
  float l_part[2] = {0.f, 0.f};

  const int nch = 4 * qt + 4;

  // 20 DMA instrs per chunk over 8 waves (waves 0-3: 3, waves 4-7: 2;
  // per-wave vmcnt(0) needs no uniformity). j 0..9 -> K, 10..19 -> V.
#define STAGE_CHUNK(c)                                                         \
  do {                                                                         \
    const int buf_ = (c) & 1;                                                  \
    const unsigned short* Kt_ = Krow + (size_t)(c) * 64 * HD_;                 \
    const unsigned short* Vt_ = Vtile + (size_t)(c) * 5120;                    \
    _Pragma("unroll")                                                          \
    for (int u_ = 0; u_ < 3; ++u_) {                                           \
      const int j_ = u_ * 8 + wave;                                            \
      if (j_ < 10)      GLOAD_LDS16(Kt_ + j_ * 512 + lane * 8,                 \
                                    &Ks[buf_][j_ * 512]);                      \
      else if (j_ < 20) GLOAD_LDS16(Vt_ + (j_ - 10) * 512 + lane * 8,          \
                                    &Vs[buf_][(j_ - 10) * 512]);               \
    }                                                                          \
  } while (0)

  STAGE_CHUNK(0);

  for (int c = 0; c < nch; c++) {
    const int k0 = c * 64;
    const int buf = c & 1;
    asm volatile("s_waitcnt vmcnt(0)" ::: "memory");  // chunk c landed (issued 1 chunk ago)
    __builtin_amdgcn_s_barrier();                     // all waves: c landed, c-1 reads done
    if (c + 1 < nch) STAGE_CHUNK(c + 1);
    const bool diag = (k0 + 63 > qbase);

    // two 32-key halves: QK -> softmax -> PV (accST peak 16 regs)
#pragma unroll
    for (int hh = 0; hh < 2; hh++) {
      floatx4 accST[2][2] = {};
#pragma unroll
      for (int nl = 0; nl < 2; nl++) {
        const int ni = hh * 2 + nl;
        const unsigned short* kp = &Ks[buf][(ni * 16 + fr) * 80];
        const short8 kf0 = *(const short8*)&kp[fg * 8];
        const short8 kf1 = *(const short8*)&kp[32 + fg * 8];
        const short8 kf2 = *(const short8*)&kp[64 + (fg & 1) * 8];  // fg>=2: qf side is zero
        accST[nl][0] = __builtin_amdgcn_mfma_f32_16x16x32_bf16(kf0, qf[0][0], accST[nl][0], 0, 0, 0);
        accST[nl][1] = __builtin_amdgcn_mfma_f32_16x16x32_bf16(kf0, qf[1][0], accST[nl][1], 0, 0, 0);
        accST[nl][0] = __builtin_amdgcn_mfma_f32_16x16x32_bf16(kf1, qf[0][1], accST[nl][0], 0, 0, 0);
        accST[nl][1] = __builtin_amdgcn_mfma_f32_16x16x32_bf16(kf1, qf[1][1], accST[nl][1], 0, 0, 0);
        accST[nl][0] = __builtin_amdgcn_mfma_f32_16x16x32_bf16(kf2, qf[0][2], accST[nl][0], 0, 0, 0);
        accST[nl][1] = __builtin_amdgcn_mfma_f32_16x16x32_bf16(kf2, qf[1][2], accST[nl][1], 0, 0, 0);
      }
      if (diag) {
#pragma unroll
        for (int nl = 0; nl < 2; nl++)
#pragma unroll
          for (int mi = 0; mi < 2; mi++) {
            const int qg = qbase + mi * 16 + fr;
#pragma unroll
            for (int r = 0; r < 4; r++) {
              const int kg = k0 + (hh * 2 + nl) * 16 + fg * 4 + r;
              if (kg > qg) accST[nl][mi][r] = -1e30f;
            }
          }
      }
#pragma unroll
      for (int nl = 0; nl < 2; nl++)
#pragma unroll
        for (int mi = 0; mi < 2; mi++) {
          const float p0 = __builtin_amdgcn_exp2f(accST[nl][mi][0]);
          const float p1 = __builtin_amdgcn_exp2f(accST[nl][mi][1]);
          const float p2 = __builtin_amdgcn_exp2f(accST[nl][mi][2]);
          const float p3 = __builtin_amdgcn_exp2f(accST[nl][mi][3]);
          l_part[mi] += (p0 + p1) + (p2 + p3);
          uint2 w;
          w.x = (unsigned)f2bf(p0) | ((unsigned)f2bf(p1) << 16);
          w.y = (unsigned)f2bf(p2) | ((unsigned)f2bf(p3) << 16);
          *(uint2*)&Ts[wave][(mi * 16 + fr) * 40 + nl * 16 + fg * 4] = w;
        }
      // wave-local write->read; compiler inserts lgkmcnt
      const short8 pf0 = *(const short8*)&Ts[wave][fr * 40 + fg * 8];
      const short8 pf1 = *(const short8*)&Ts[wave][(16 + fr) * 40 + fg * 8];
      const int vcol = hh * 32 + fg * 8;
#pragma unroll
      for (int dt = 0; dt < 5; dt++) {
        const short8 vf = *(const short8*)&Vs[buf][(dt * 16 + fr) * 64 + (vcol ^ ((fr & 7) * 8))];
        accOT[dt][0] = __builtin_amdgcn_mfma_f32_16x16x32_bf16(vf, pf0, accOT[dt][0], 0, 0, 0);
        accOT[dt][1] = __builtin_amdgcn_mfma_f32_16x16x32_bf16(vf, pf1, accOT[dt][1], 0, 0, 0);
      }
    }
  }
#undef STAGE_CHUNK

  // epilogue: l reduce across fg lanes; packed b64 ctx stores (4 consecutive d)
  const int b = bh >> 5, h2 = bh & 31;
#pragma unroll
  for (int mi = 0; mi < 2; mi++) {
    float s = l_part[mi];
    s += __shfl_xor(s, 16);
    s += __shfl_xor(s, 32);
    const float inv = 1.f / s;
    const size_t rowoff = (size_t)(b * S_ + qbase + mi * 16 + fr) * D_ + h2 * HD_;
#pragma unroll
    for (int dt = 0; dt < 5; dt++) {
      const float v0 = accOT[dt][mi][0] * inv;
      const float v1 = accOT[dt][mi][1] * inv;
      const float v2 = accOT[dt][mi][2] * inv;
      const float v3 = accOT[dt][mi][3] * inv;
      uint2 w;
      w.x = (unsigned)f2bf(v0) | ((unsigned)f2bf(v1) << 16);
      w.y = (unsigned)f2bf(v2) | ((unsigned)f2bf(v3) << 16);
      *(uint2*)&ctx[rowoff + dt * 16 + fg * 4] = w;
    }
  }
}

extern "C" void kernel_launch(void* const* d_in, const int* in_sizes, int n_in,
                              void* d_out, int out_size, void* d_ws, size_t ws_size,
                              hipStream_t stream) {
  (void)in_sizes; (void)n_in; (void)out_size; (void)ws_size;
  const float* x      = (const float*)d_in[0];
  const float* wqkv_w = (const float*)d_in[1];
  const float* wqkv_b = (const float*)d_in[2];
  const float* out_w  = (const float*)d_in[3];
  const float* out_b  = (const float*)d_in[4];
  char* ws = (char*)d_ws;

  unsigned short* Xb    = (unsigned short*)(ws + 0);          // 4096x2560 bf16
  unsigned short* Wqkvb = (unsigned short*)(ws + 20971520);   // 7680x2560 bf16 (dead after gemm1)
  unsigned short* qkv   = (unsigned short*)(ws + 60293120);   // 4096x7680 bf16
  unsigned short* Qb    = (unsigned short*)(ws + 123207680);  // [B,H,S,80] bf16
  unsigned short* Kb    = (unsigned short*)(ws + 144179200);  // [B,H,S,80] bf16
  unsigned short* Woutb = (unsigned short*)(ws + 165150720);  // 2560x2560 bf16; end 178.3 MB
  unsigned short* ctx   = Xb;                                 // Xb dead after gemm1
  unsigned short* Vtile = (unsigned short*)(ws + 34078720);   // 21.0 MB in dead Wqkvb tail

  cvt3_kernel<<<35840, 256, 0, stream>>>(x, Xb, 2621440,
                                         wqkv_w, Wqkvb, 4915200,
                                         out_w, Woutb, 1638400);
  gemm256<1, 8, 4><<<dim3(30, 16), 512, 0, stream>>>(Xb, Wqkvb, wqkv_b, (void*)qkv, 4096, 7680, 2560);
  rope_kernel<<<512, 256, 0, stream>>>(qkv, Qb, Kb);
  vtrans_kernel<<<dim3(32, 64), 256, 0, stream>>>(qkv, Vtile);
  attn_mfma<<<dim3(8, 64), 512, 0, stream>>>(Qb, Kb, Vtile, ctx);
  gemm256<0, 8, 4><<<dim3(10, 16), 512, 0, stream>>>(ctx, Woutb, out_b, d_out, 4096, 2560, 2560);
}